// Round 14
// baseline (221.961 us; speedup 1.0000x reference)
//
#include <hip/hip_runtime.h>
#include <hip/hip_fp16.h>

// GIN: h1 = relu((scatter_add(x) + (1+eps0)*x) @ W0^T)
//      h2 = relu((scatter_add(h1) + (1+eps1)*h1) @ W1^T)
//      out = (h1 @ Wm^T + h2) / 2
//
// R14: XCD-partitioned rank histogram. R13's hist_rank (68us, VALU 0.2%,
// occ 12%) is bound by cross-XCD atomic line ping-pong (100k counters x 16
// hits each from all 8 XCDs). Now: 8 partition counters cnt[p][n] with
// p = histBlock & 7 (blockIdx%8 ~ XCD round-robin -> partition-local L2
// atomics). rank stored as ushort (3.2MB, was 6.4MB int) exactly pays for
// cnt (3.2MB): ws stays ~39.4MB. Reconstruction: reduce_poff (partition
// prefix -> deg), scan (unchanged), addoff (off folded into partition
// bases), fill computes p=(e>>12)&7. Fused kernels = R13-proven (grid 2048).

#define HIST_EPT 16            // edges per thread in hist
#define HIST_EPB 4096          // 256 threads * 16 = edges per hist block
#define NPART 8

// ================================================================ prelude
__global__ __launch_bounds__(256) void zero_convert_kernel(
    int* __restrict__ cnt, int cntTotal,
    const float* __restrict__ in, __half* __restrict__ outh, int total4)
{
    int i = blockIdx.x * blockDim.x + threadIdx.x;
    int stride = gridDim.x * blockDim.x;
    for (int k = i; k < cntTotal; k += stride) cnt[k] = 0;
    const float4* in4 = (const float4*)in;
    uint2* out4 = (uint2*)outh;
    for (int k = i; k < total4; k += stride) {
        float4 v = in4[k];
        __half2 a = __floats2half2_rn(v.x, v.y);
        __half2 b = __floats2half2_rn(v.z, v.w);
        uint2 u;
        u.x = __builtin_bit_cast(unsigned int, a);
        u.y = __builtin_bit_cast(unsigned int, b);
        out4[k] = u;
    }
}

__global__ __launch_bounds__(256) void zero_int_kernel(int* __restrict__ p, int n)
{
    int i = blockIdx.x * blockDim.x + threadIdx.x;
    int stride = gridDim.x * blockDim.x;
    for (; i < n; i += stride) p[i] = 0;
}

// ================================================================ partitioned rank histogram
__global__ __launch_bounds__(256) void hist_rank_part_kernel(
    const int* __restrict__ dst, int* __restrict__ cnt,
    unsigned short* __restrict__ rank16, int E, int n)
{
    int b = blockIdx.x;
    int* cp = cnt + (size_t)(b & (NPART - 1)) * n;
    int base = b * HIST_EPB + threadIdx.x * HIST_EPT;
    if (base + HIST_EPT - 1 < E) {
        int4 a = *(const int4*)&dst[base];
        int4 bb = *(const int4*)&dst[base + 4];
        int4 c = *(const int4*)&dst[base + 8];
        int4 d = *(const int4*)&dst[base + 12];
        unsigned int r0 = (unsigned int)atomicAdd(&cp[a.x], 1);
        unsigned int r1 = (unsigned int)atomicAdd(&cp[a.y], 1);
        unsigned int r2 = (unsigned int)atomicAdd(&cp[a.z], 1);
        unsigned int r3 = (unsigned int)atomicAdd(&cp[a.w], 1);
        unsigned int r4 = (unsigned int)atomicAdd(&cp[bb.x], 1);
        unsigned int r5 = (unsigned int)atomicAdd(&cp[bb.y], 1);
        unsigned int r6 = (unsigned int)atomicAdd(&cp[bb.z], 1);
        unsigned int r7 = (unsigned int)atomicAdd(&cp[bb.w], 1);
        unsigned int r8 = (unsigned int)atomicAdd(&cp[c.x], 1);
        unsigned int r9 = (unsigned int)atomicAdd(&cp[c.y], 1);
        unsigned int rA = (unsigned int)atomicAdd(&cp[c.z], 1);
        unsigned int rB = (unsigned int)atomicAdd(&cp[c.w], 1);
        unsigned int rC = (unsigned int)atomicAdd(&cp[d.x], 1);
        unsigned int rD = (unsigned int)atomicAdd(&cp[d.y], 1);
        unsigned int rE = (unsigned int)atomicAdd(&cp[d.z], 1);
        unsigned int rF = (unsigned int)atomicAdd(&cp[d.w], 1);
        uint4 w0, w1;
        w0.x = (r1 << 16) | (r0 & 0xffffu);
        w0.y = (r3 << 16) | (r2 & 0xffffu);
        w0.z = (r5 << 16) | (r4 & 0xffffu);
        w0.w = (r7 << 16) | (r6 & 0xffffu);
        w1.x = (r9 << 16) | (r8 & 0xffffu);
        w1.y = (rB << 16) | (rA & 0xffffu);
        w1.z = (rD << 16) | (rC & 0xffffu);
        w1.w = (rF << 16) | (rE & 0xffffu);
        *(uint4*)&rank16[base] = w0;
        *(uint4*)&rank16[base + 8] = w1;
    } else {
        for (int e = base; e < E; ++e)
            rank16[e] = (unsigned short)atomicAdd(&cp[dst[e]], 1);
    }
}

// per-node: exclusive prefix over partitions (in place) + deg = total
__global__ __launch_bounds__(256) void reduce_poff_kernel(
    int* __restrict__ cnt, int* __restrict__ deg, int n)
{
    int d = blockIdx.x * blockDim.x + threadIdx.x;
    if (d >= n) return;
    int run = 0;
#pragma unroll
    for (int p = 0; p < NPART; ++p) {
        size_t idx = (size_t)p * n + d;
        int t = cnt[idx];
        cnt[idx] = run;
        run += t;
    }
    deg[d] = run;
}

// fold off[d] into all partition bases
__global__ __launch_bounds__(256) void addoff_kernel(
    int* __restrict__ cnt, const int* __restrict__ off, int n)
{
    int d = blockIdx.x * blockDim.x + threadIdx.x;
    if (d >= n) return;
    int o = off[d];
#pragma unroll
    for (int p = 0; p < NPART; ++p) cnt[(size_t)p * n + d] += o;
}

// ================================================================ scans (R5-proven)
__global__ __launch_bounds__(256) void scanA_kernel(
    const int* __restrict__ deg, int* __restrict__ off,
    int* __restrict__ bsum, int n)
{
    __shared__ int tmp[256];
    int t = threadIdx.x;
    int base = blockIdx.x * 1024 + t * 4;
    int v0 = 0, v1 = 0, v2 = 0, v3 = 0;
    if (base + 3 < n) {
        int4 q = *(const int4*)&deg[base];
        v0 = q.x; v1 = q.y; v2 = q.z; v3 = q.w;
    } else {
        if (base + 0 < n) v0 = deg[base + 0];
        if (base + 1 < n) v1 = deg[base + 1];
        if (base + 2 < n) v2 = deg[base + 2];
    }
    int tot = v0 + v1 + v2 + v3;
    tmp[t] = tot;
    __syncthreads();
    for (int d = 1; d < 256; d <<= 1) {
        int x = (t >= d) ? tmp[t - d] : 0;
        __syncthreads();
        tmp[t] += x;
        __syncthreads();
    }
    int incl = tmp[t];
    int p = incl - tot;
    if (base + 0 < n) off[base + 0] = p;
    if (base + 1 < n) off[base + 1] = p + v0;
    if (base + 2 < n) off[base + 2] = p + v0 + v1;
    if (base + 3 < n) off[base + 3] = p + v0 + v1 + v2;
    if (t == 255) bsum[blockIdx.x] = incl;
}

__global__ __launch_bounds__(256) void scanB_kernel(int* __restrict__ bsum, int nb)
{
    __shared__ int tmp[256];
    int t = threadIdx.x;
    int v = (t < nb) ? bsum[t] : 0;
    tmp[t] = v;
    __syncthreads();
    for (int d = 1; d < 256; d <<= 1) {
        int x = (t >= d) ? tmp[t - d] : 0;
        __syncthreads();
        tmp[t] += x;
        __syncthreads();
    }
    if (t < nb) bsum[t] = tmp[t] - v;
}

__global__ __launch_bounds__(256) void scanC_kernel(
    int* __restrict__ off, int* __restrict__ cursor,
    const int* __restrict__ bsum, int n, int E)
{
    int t = threadIdx.x;
    int add = bsum[blockIdx.x];
    int base = blockIdx.x * 1024 + t * 4;
#pragma unroll
    for (int q = 0; q < 4; ++q) {
        int idx = base + q;
        if (idx < n) {
            int v = off[idx] + add;
            off[idx] = v;
            if (cursor) cursor[idx] = v;
        }
    }
    if (blockIdx.x == 0 && t == 0) off[n] = E;
}

// ================================================================ fill (partitioned, atomic-free)
__global__ __launch_bounds__(256) void fill_rank_part_kernel(
    const int* __restrict__ src, const int* __restrict__ dst,
    const unsigned short* __restrict__ rank16, const int* __restrict__ cnt,
    int* __restrict__ bucket, int E, int n)
{
    int base = (blockIdx.x * blockDim.x + threadIdx.x) * 8;
    if (base + 7 < E) {
        // 8 consecutive edges never straddle a 4096-edge hist block (8 | 4096)
        const int* cp = cnt + (size_t)((base >> 12) & (NPART - 1)) * n;
        int4 d0 = *(const int4*)&dst[base];
        int4 d1 = *(const int4*)&dst[base + 4];
        uint4 r = *(const uint4*)&rank16[base];   // 8 ushorts
        int4 s0 = *(const int4*)&src[base];
        int4 s1 = *(const int4*)&src[base + 4];
        bucket[cp[d0.x] + (int)(r.x & 0xffffu)] = s0.x;
        bucket[cp[d0.y] + (int)(r.x >> 16)]     = s0.y;
        bucket[cp[d0.z] + (int)(r.y & 0xffffu)] = s0.z;
        bucket[cp[d0.w] + (int)(r.y >> 16)]     = s0.w;
        bucket[cp[d1.x] + (int)(r.z & 0xffffu)] = s1.x;
        bucket[cp[d1.y] + (int)(r.z >> 16)]     = s1.y;
        bucket[cp[d1.z] + (int)(r.w & 0xffffu)] = s1.z;
        bucket[cp[d1.w] + (int)(r.w >> 16)]     = s1.w;
    } else {
        for (int e = base; e < E; ++e) {
            const int* cp = cnt + (size_t)((e >> 12) & (NPART - 1)) * n;
            bucket[cp[dst[e]] + (int)rank16[e]] = src[e];
        }
    }
}

// ================================================================ tier B CSR (cursor-based)
__global__ __launch_bounds__(256) void hist_kernel(
    const int* __restrict__ dst, int* __restrict__ deg, int E)
{
    int e4 = (blockIdx.x * blockDim.x + threadIdx.x) * 4;
    if (e4 + 3 < E) {
        int4 d = *(const int4*)&dst[e4];
        atomicAdd(&deg[d.x], 1);
        atomicAdd(&deg[d.y], 1);
        atomicAdd(&deg[d.z], 1);
        atomicAdd(&deg[d.w], 1);
    } else {
        for (int e = e4; e < E; ++e) atomicAdd(&deg[dst[e]], 1);
    }
}

__global__ __launch_bounds__(256) void fill_kernel(
    const int* __restrict__ src, const int* __restrict__ dst,
    int* __restrict__ cursor, int* __restrict__ bucket, int E)
{
    int e = blockIdx.x * blockDim.x + threadIdx.x;
    if (e < E) {
        int d = dst[e];
        int p = atomicAdd(&cursor[d], 1);
        bucket[p] = src[e];
    }
}

// ================================================================ helpers
#define WPB 8  // waves per 512-thread block

__device__ __forceinline__ __half2 bc_h2(unsigned int u)
{
    return __builtin_bit_cast(__half2, u);
}
__device__ __forceinline__ unsigned int bc_u(__half2 h)
{
    return __builtin_bit_cast(unsigned int, h);
}

#if __has_builtin(__builtin_amdgcn_fdot2)
typedef _Float16 half2_v __attribute__((ext_vector_type(2)));
__device__ __forceinline__ float fdot2(unsigned int a, unsigned int b, float c)
{
    return __builtin_amdgcn_fdot2(__builtin_bit_cast(half2_v, a),
                                  __builtin_bit_cast(half2_v, b), c, false);
}
#else
__device__ __forceinline__ float fdot2(unsigned int a, unsigned int b, float c)
{
    float2 af = __half22float2(bc_h2(a));
    float2 bf = __half22float2(bc_h2(b));
    return fmaf(af.x, bf.x, fmaf(af.y, bf.y, c));
}
#endif

// ================================================================ tier A fused kernels (R10/R13-proven)
__device__ __forceinline__ void xreduce4(__half2& a0, __half2& a1,
                                         __half2& a2, __half2& a3)
{
#pragma unroll
    for (int mask = 8; mask <= 32; mask <<= 1) {
        a0 = __hadd2(a0, bc_h2((unsigned int)__shfl_xor((int)bc_u(a0), mask, 64)));
        a1 = __hadd2(a1, bc_h2((unsigned int)__shfl_xor((int)bc_u(a1), mask, 64)));
        a2 = __hadd2(a2, bc_h2((unsigned int)__shfl_xor((int)bc_u(a2), mask, 64)));
        a3 = __hadd2(a3, bc_h2((unsigned int)__shfl_xor((int)bc_u(a3), mask, 64)));
    }
}

__device__ __forceinline__ void gather8(
    const __half* __restrict__ hh, const int* __restrict__ bucket,
    int beg, int end, int g, int l8,
    __half2& a0, __half2& a1, __half2& a2, __half2& a3)
{
    int j = beg;
    for (; j + 16 <= end; j += 16) {
        int sa = bucket[j + g];
        int sb = bucket[j + 8 + g];
        uint4 va = *(const uint4*)&hh[(size_t)sa * 64 + l8 * 8];
        uint4 vb = *(const uint4*)&hh[(size_t)sb * 64 + l8 * 8];
        a0 = __hadd2(__hadd2(a0, bc_h2(va.x)), bc_h2(vb.x));
        a1 = __hadd2(__hadd2(a1, bc_h2(va.y)), bc_h2(vb.y));
        a2 = __hadd2(__hadd2(a2, bc_h2(va.z)), bc_h2(vb.z));
        a3 = __hadd2(__hadd2(a3, bc_h2(va.w)), bc_h2(vb.w));
    }
    if (j + 8 <= end) {
        int sa = bucket[j + g];
        uint4 va = *(const uint4*)&hh[(size_t)sa * 64 + l8 * 8];
        a0 = __hadd2(a0, bc_h2(va.x));
        a1 = __hadd2(a1, bc_h2(va.y));
        a2 = __hadd2(a2, bc_h2(va.z));
        a3 = __hadd2(a3, bc_h2(va.w));
        j += 8;
    }
    if (j < end) {
        int jj = j + g;
        int sc = bucket[(jj < end) ? jj : (end - 1)];
        __half2 m2 = __float2half2_rn((jj < end) ? 1.0f : 0.0f);
        uint4 vc = *(const uint4*)&hh[(size_t)sc * 64 + l8 * 8];
        a0 = __hfma2(bc_h2(vc.x), m2, a0);
        a1 = __hfma2(bc_h2(vc.y), m2, a1);
        a2 = __hfma2(bc_h2(vc.z), m2, a2);
        a3 = __hfma2(bc_h2(vc.w), m2, a3);
    }
}

__global__ __launch_bounds__(512) void fused_gin_h_kernel(
    const __half* __restrict__ hh, const int* __restrict__ off,
    const int* __restrict__ bucket, const float* __restrict__ W,
    const float* __restrict__ eps, __half* __restrict__ outh, int n)
{
    __shared__ __half WhS[4096];       // [k4][row][e] fp16
    __shared__ __half rowh[WPB][64];
    int tid = threadIdx.x;
    for (int idx = tid; idx < 4096; idx += 512) {
        int row = idx >> 6, col = idx & 63;
        WhS[(col >> 3) * 512 + row * 8 + (col & 7)] = __float2half(W[idx]);
    }
    __syncthreads();
    float s = 1.0f + eps[0];
    __half2 s2 = __float2half2_rn(s);
    int lane = tid & 63;
    int w = tid >> 6;
    int l8 = lane & 7;
    int g = lane >> 3;
    int wavesTotal = gridDim.x * WPB;
    const uint4* Wh4 = (const uint4*)WhS;
    for (int i = blockIdx.x * WPB + w; i < n; i += wavesTotal) {
        int2 be = *(const int2*)&off[i];
        int beg = __builtin_amdgcn_readfirstlane(be.x);
        int end = __builtin_amdgcn_readfirstlane(be.y);
        __half2 a0 = bc_h2(0u), a1 = bc_h2(0u), a2 = bc_h2(0u), a3 = bc_h2(0u);
        gather8(hh, bucket, beg, end, g, l8, a0, a1, a2, a3);
        xreduce4(a0, a1, a2, a3);
        if (g == 0) {
            uint4 sv = *(const uint4*)&hh[(size_t)i * 64 + l8 * 8];
            a0 = __hfma2(bc_h2(sv.x), s2, a0);
            a1 = __hfma2(bc_h2(sv.y), s2, a1);
            a2 = __hfma2(bc_h2(sv.z), s2, a2);
            a3 = __hfma2(bc_h2(sv.w), s2, a3);
            uint4 st;
            st.x = bc_u(a0); st.y = bc_u(a1); st.z = bc_u(a2); st.w = bc_u(a3);
            *(uint4*)&rowh[w][l8 * 8] = st;
        }
        __builtin_amdgcn_wave_barrier();
        float o = 0.f;
#pragma unroll
        for (int k4 = 0; k4 < 8; ++k4) {
            uint4 wv = Wh4[k4 * 64 + lane];
            uint4 rv = *(const uint4*)&rowh[w][k4 * 8];
            o = fdot2(wv.x, rv.x, o);
            o = fdot2(wv.y, rv.y, o);
            o = fdot2(wv.z, rv.z, o);
            o = fdot2(wv.w, rv.w, o);
        }
        outh[(size_t)i * 64 + lane] = __float2half(fmaxf(o, 0.f));
        __builtin_amdgcn_wave_barrier();
    }
}

__global__ __launch_bounds__(512) void fused_final_h_kernel(
    const __half* __restrict__ hh1, const int* __restrict__ off,
    const int* __restrict__ bucket, const float* __restrict__ W1,
    const float* __restrict__ Wm, const float* __restrict__ eps,
    float* __restrict__ out, int n)
{
    __shared__ __half W1hS[4096];
    __shared__ __half WmhS[4096];
    __shared__ __half rowh[WPB][64];
    __shared__ __half selfh[WPB][64];
    int tid = threadIdx.x;
    for (int idx = tid; idx < 4096; idx += 512) {
        int row = idx >> 6, col = idx & 63;
        int li = (col >> 3) * 512 + row * 8 + (col & 7);
        W1hS[li] = __float2half(W1[idx]);
        WmhS[li] = __float2half(Wm[idx]);
    }
    __syncthreads();
    float s = 1.0f + eps[0];
    __half2 s2 = __float2half2_rn(s);
    int lane = tid & 63;
    int w = tid >> 6;
    int l8 = lane & 7;
    int g = lane >> 3;
    int wavesTotal = gridDim.x * WPB;
    const uint4* W1h4 = (const uint4*)W1hS;
    const uint4* Wmh4 = (const uint4*)WmhS;
    for (int i = blockIdx.x * WPB + w; i < n; i += wavesTotal) {
        int2 be = *(const int2*)&off[i];
        int beg = __builtin_amdgcn_readfirstlane(be.x);
        int end = __builtin_amdgcn_readfirstlane(be.y);
        __half2 a0 = bc_h2(0u), a1 = bc_h2(0u), a2 = bc_h2(0u), a3 = bc_h2(0u);
        gather8(hh1, bucket, beg, end, g, l8, a0, a1, a2, a3);
        xreduce4(a0, a1, a2, a3);
        if (g == 0) {
            uint4 sv = *(const uint4*)&hh1[(size_t)i * 64 + l8 * 8];
            *(uint4*)&selfh[w][l8 * 8] = sv;
            a0 = __hfma2(bc_h2(sv.x), s2, a0);
            a1 = __hfma2(bc_h2(sv.y), s2, a1);
            a2 = __hfma2(bc_h2(sv.z), s2, a2);
            a3 = __hfma2(bc_h2(sv.w), s2, a3);
            uint4 st;
            st.x = bc_u(a0); st.y = bc_u(a1); st.z = bc_u(a2); st.w = bc_u(a3);
            *(uint4*)&rowh[w][l8 * 8] = st;
        }
        __builtin_amdgcn_wave_barrier();
        float o1 = 0.f, o2 = 0.f;
#pragma unroll
        for (int k4 = 0; k4 < 8; ++k4) {
            uint4 wv1 = W1h4[k4 * 64 + lane];
            uint4 wv2 = Wmh4[k4 * 64 + lane];
            uint4 rv  = *(const uint4*)&rowh[w][k4 * 8];
            uint4 sv  = *(const uint4*)&selfh[w][k4 * 8];
            o1 = fdot2(wv1.x, rv.x, o1);
            o1 = fdot2(wv1.y, rv.y, o1);
            o1 = fdot2(wv1.z, rv.z, o1);
            o1 = fdot2(wv1.w, rv.w, o1);
            o2 = fdot2(wv2.x, sv.x, o2);
            o2 = fdot2(wv2.y, sv.y, o2);
            o2 = fdot2(wv2.z, sv.z, o2);
            o2 = fdot2(wv2.w, sv.w, o2);
        }
        out[(size_t)i * 64 + lane] = (fmaxf(o1, 0.f) + o2) * 0.5f;
        __builtin_amdgcn_wave_barrier();
    }
}

// ================================================================ tier B: fp32 fused (R6-proven)
__device__ __forceinline__ float dot4(float4 a, float4 b)
{
    return a.x * b.x + a.y * b.y + a.z * b.z + a.w * b.w;
}

__device__ __forceinline__ float4 gather_row_f32(
    const float* __restrict__ h, const int* __restrict__ bucket,
    int beg, int end, int g, int l16, float4 acc4)
{
    int j = beg;
    for (; j + 8 <= end; j += 8) {
        int sa = bucket[j + g];
        int sb = bucket[j + 4 + g];
        float4 va = *(const float4*)&h[(size_t)sa * 64 + l16 * 4];
        float4 vb = *(const float4*)&h[(size_t)sb * 64 + l16 * 4];
        acc4.x += va.x + vb.x;
        acc4.y += va.y + vb.y;
        acc4.z += va.z + vb.z;
        acc4.w += va.w + vb.w;
    }
    if (j + 4 <= end) {
        int sa = bucket[j + g];
        float4 va = *(const float4*)&h[(size_t)sa * 64 + l16 * 4];
        acc4.x += va.x; acc4.y += va.y; acc4.z += va.z; acc4.w += va.w;
        j += 4;
    }
    if (j < end) {
        int jj = j + g;
        int sc = bucket[(jj < end) ? jj : (end - 1)];
        float m = (jj < end) ? 1.0f : 0.0f;
        float4 vc = *(const float4*)&h[(size_t)sc * 64 + l16 * 4];
        acc4.x = fmaf(vc.x, m, acc4.x);
        acc4.y = fmaf(vc.y, m, acc4.y);
        acc4.z = fmaf(vc.z, m, acc4.z);
        acc4.w = fmaf(vc.w, m, acc4.w);
    }
    return acc4;
}

__global__ __launch_bounds__(512) void fused_gin_kernel(
    const float* __restrict__ h, const int* __restrict__ off,
    const int* __restrict__ bucket, const float* __restrict__ W,
    const float* __restrict__ eps, float* __restrict__ out, int n)
{
    __shared__ float Ws[64][68];
    __shared__ float P[WPB][4][64];
    __shared__ float rowbuf[WPB][64];
    int tid = threadIdx.x;
    for (int idx = tid; idx < 4096; idx += 512) Ws[idx >> 6][idx & 63] = W[idx];
    __syncthreads();
    float s = 1.0f + eps[0];
    int lane = tid & 63;
    int w = tid >> 6;
    int l16 = lane & 15;
    int g = lane >> 4;
    int wavesTotal = gridDim.x * WPB;
    for (int i = blockIdx.x * WPB + w; i < n; i += wavesTotal) {
        float4 init = make_float4(0.f, 0.f, 0.f, 0.f);
        if (g == 0) {
            float4 self4 = *(const float4*)&h[(size_t)i * 64 + l16 * 4];
            init = make_float4(s * self4.x, s * self4.y, s * self4.z, s * self4.w);
        }
        int2 be = *(const int2*)&off[i];
        int beg = __builtin_amdgcn_readfirstlane(be.x);
        int end = __builtin_amdgcn_readfirstlane(be.y);
        float4 acc4 = gather_row_f32(h, bucket, beg, end, g, l16, init);
        *(float4*)&P[w][g][l16 * 4] = acc4;
        __builtin_amdgcn_wave_barrier();
        float r0 = P[w][0][lane], r1 = P[w][1][lane];
        float r2 = P[w][2][lane], r3 = P[w][3][lane];
        rowbuf[w][lane] = (r0 + r1) + (r2 + r3);
        __builtin_amdgcn_wave_barrier();
        const float4* wrow = (const float4*)&Ws[lane][0];
        const float4* rrow = (const float4*)&rowbuf[w][0];
        float o = 0.f;
#pragma unroll
        for (int k4 = 0; k4 < 16; ++k4) o += dot4(wrow[k4], rrow[k4]);
        out[(size_t)i * 64 + lane] = fmaxf(o, 0.f);
        __builtin_amdgcn_wave_barrier();
    }
}

__global__ __launch_bounds__(512) void fused_final_csr_kernel(
    const float* __restrict__ h1, const int* __restrict__ off,
    const int* __restrict__ bucket, const float* __restrict__ W1,
    const float* __restrict__ Wm, const float* __restrict__ eps,
    float* __restrict__ out, int n)
{
    __shared__ float W1s[64][68];
    __shared__ float Wms[64][68];
    __shared__ float P[WPB][4][64];
    __shared__ float rowbuf[WPB][64];
    __shared__ float selfbuf[WPB][64];
    int tid = threadIdx.x;
    for (int idx = tid; idx < 4096; idx += 512) {
        W1s[idx >> 6][idx & 63] = W1[idx];
        Wms[idx >> 6][idx & 63] = Wm[idx];
    }
    __syncthreads();
    float s = 1.0f + eps[0];
    int lane = tid & 63;
    int w = tid >> 6;
    int l16 = lane & 15;
    int g = lane >> 4;
    int wavesTotal = gridDim.x * WPB;
    for (int i = blockIdx.x * WPB + w; i < n; i += wavesTotal) {
        float4 init = make_float4(0.f, 0.f, 0.f, 0.f);
        if (g == 0) {
            float4 self4 = *(const float4*)&h1[(size_t)i * 64 + l16 * 4];
            *(float4*)&selfbuf[w][l16 * 4] = self4;
            init = make_float4(s * self4.x, s * self4.y, s * self4.z, s * self4.w);
        }
        int2 be = *(const int2*)&off[i];
        int beg = __builtin_amdgcn_readfirstlane(be.x);
        int end = __builtin_amdgcn_readfirstlane(be.y);
        float4 acc4 = gather_row_f32(h1, bucket, beg, end, g, l16, init);
        *(float4*)&P[w][g][l16 * 4] = acc4;
        __builtin_amdgcn_wave_barrier();
        float r0 = P[w][0][lane], r1 = P[w][1][lane];
        float r2 = P[w][2][lane], r3 = P[w][3][lane];
        rowbuf[w][lane] = (r0 + r1) + (r2 + r3);
        __builtin_amdgcn_wave_barrier();
        const float4* w1row = (const float4*)&W1s[lane][0];
        const float4* wmrow = (const float4*)&Wms[lane][0];
        const float4* rrow  = (const float4*)&rowbuf[w][0];
        const float4* srow  = (const float4*)&selfbuf[w][0];
        float o1 = 0.f, o2 = 0.f;
#pragma unroll
        for (int k4 = 0; k4 < 16; ++k4) {
            o1 += dot4(w1row[k4], rrow[k4]);
            o2 += dot4(wmrow[k4], srow[k4]);
        }
        out[(size_t)i * 64 + lane] = (fmaxf(o1, 0.f) + o2) * 0.5f;
        __builtin_amdgcn_wave_barrier();
    }
}

// ================================================================ tier C: atomic scatter
__global__ __launch_bounds__(256) void init_scale_kernel(
    const float* __restrict__ h, const float* __restrict__ eps,
    float* __restrict__ agg, int total4)
{
    float s = 1.0f + eps[0];
    int i = blockIdx.x * blockDim.x + threadIdx.x;
    int stride = gridDim.x * blockDim.x;
    const float4* h4 = (const float4*)h;
    float4* a4 = (float4*)agg;
    for (; i < total4; i += stride) {
        float4 v = h4[i];
        v.x *= s; v.y *= s; v.z *= s; v.w *= s;
        a4[i] = v;
    }
}

__global__ __launch_bounds__(256) void scatter_kernel(
    const float* __restrict__ h, const int* __restrict__ src,
    const int* __restrict__ dst, float* __restrict__ agg, int E)
{
    int lane = threadIdx.x & 63;
    int e = blockIdx.x * 4 + (threadIdx.x >> 6);
    if (e >= E) return;
    int s = src[e];
    int d = dst[e];
    atomicAdd(&agg[(size_t)d * 64 + lane], h[(size_t)s * 64 + lane]);
}

__global__ __launch_bounds__(256) void gemm_relu_kernel(
    const float* __restrict__ A, const float* __restrict__ W,
    float* __restrict__ out, int n)
{
    __shared__ float Wt[64][65];
    __shared__ float rowbuf[4][64];
    int tid = threadIdx.x;
    for (int i = tid; i < 4096; i += 256) Wt[i & 63][i >> 6] = W[i];
    __syncthreads();
    int lane = tid & 63;
    int w = tid >> 6;
    int wavesTotal = gridDim.x * 4;
    for (int i = blockIdx.x * 4 + w; i < n; i += wavesTotal) {
        rowbuf[w][lane] = A[(size_t)i * 64 + lane];
        __builtin_amdgcn_wave_barrier();
        float o = 0.f;
#pragma unroll
        for (int k = 0; k < 64; ++k) o += rowbuf[w][k] * Wt[k][lane];
        out[(size_t)i * 64 + lane] = fmaxf(o, 0.f);
        __builtin_amdgcn_wave_barrier();
    }
}

__global__ __launch_bounds__(256) void final_kernel(
    const float* __restrict__ Agg, const float* __restrict__ H1,
    const float* __restrict__ W1, const float* __restrict__ Wm,
    float* __restrict__ out, int n)
{
    __shared__ float W1t[64][65];
    __shared__ float Wmt[64][65];
    __shared__ float rowbuf[4][64];
    __shared__ float selfbuf[4][64];
    int tid = threadIdx.x;
    for (int i = tid; i < 4096; i += 256) {
        W1t[i & 63][i >> 6] = W1[i];
        Wmt[i & 63][i >> 6] = Wm[i];
    }
    __syncthreads();
    int lane = tid & 63;
    int w = tid >> 6;
    int wavesTotal = gridDim.x * 4;
    for (int i = blockIdx.x * 4 + w; i < n; i += wavesTotal) {
        rowbuf[w][lane] = Agg[(size_t)i * 64 + lane];
        selfbuf[w][lane] = H1[(size_t)i * 64 + lane];
        __builtin_amdgcn_wave_barrier();
        float o1 = 0.f, o2 = 0.f;
#pragma unroll
        for (int k = 0; k < 64; ++k) {
            o1 += rowbuf[w][k] * W1t[k][lane];
            o2 += selfbuf[w][k] * Wmt[k][lane];
        }
        out[(size_t)i * 64 + lane] = (fmaxf(o1, 0.f) + o2) * 0.5f;
        __builtin_amdgcn_wave_barrier();
    }
}

// ================================================================ launch
extern "C" void kernel_launch(void* const* d_in, const int* in_sizes, int n_in,
                              void* d_out, int out_size, void* d_ws, size_t ws_size,
                              hipStream_t stream)
{
    const float* x    = (const float*)d_in[0];
    const int*   ei   = (const int*)d_in[1];
    const float* W0   = (const float*)d_in[2];
    const float* eps0 = (const float*)d_in[3];
    const float* W1   = (const float*)d_in[4];
    const float* eps1 = (const float*)d_in[5];
    const float* Wm   = (const float*)d_in[6];
    float* out = (float*)d_out;

    int n = in_sizes[0] / 64;   // 100000
    int E = in_sizes[1] / 2;    // 1600000
    const int* src = ei;
    const int* dst = ei + E;

    auto align1k = [](size_t v) { return (v + 1023) & ~(size_t)1023; };

    // ---- tier A layout (fp16 mirrors + partitioned CSR; ~39.4 MB)
    size_t hhx_off    = 0;
    size_t hh1_off    = align1k(hhx_off + (size_t)n * 64 * 2);
    size_t off_off    = align1k(hh1_off + (size_t)n * 64 * 2);
    size_t deg_off    = align1k(off_off + (size_t)(n + 1) * 4);
    size_t bsum_off   = align1k(deg_off + (size_t)n * 4);
    size_t cnt_off    = align1k(bsum_off + 256 * 4);
    size_t bucket_off = align1k(cnt_off + (size_t)NPART * n * 4);
    size_t rank_off   = align1k(bucket_off + (size_t)E * 4);
    size_t need_A2    = rank_off + (size_t)E * 2;   // rank is ushort

    // ---- tier B layout (fp32, cursor fill; ~33.2 MB)
    size_t b_h1_off     = 0;
    size_t b_off_off    = align1k(b_h1_off + (size_t)n * 64 * 4);
    size_t b_deg_off    = align1k(b_off_off + (size_t)(n + 1) * 4);
    size_t b_cursor_off = align1k(b_deg_off + (size_t)n * 4);
    size_t b_bsum_off   = align1k(b_cursor_off + (size_t)n * 4);
    size_t b_bucket_off = align1k(b_bsum_off + 256 * 4);
    size_t need_B       = b_bucket_off + (size_t)E * 4;

    int nb = (n + 1023) / 1024;               // <=256 required
    int histBlocks = (E + HIST_EPB - 1) / HIST_EPB;   // 391
    int nodeBlocks = (n + 255) / 256;
    int fillBlocks = (E + 2047) / 2048;       // 8 edges/thread
    int total4 = n * 16;

    if (ws_size >= need_A2) {
        __half* hhx  = (__half*)((char*)d_ws + hhx_off);
        __half* hh1  = (__half*)((char*)d_ws + hh1_off);
        int* off     = (int*)((char*)d_ws + off_off);
        int* deg     = (int*)((char*)d_ws + deg_off);
        int* bsum    = (int*)((char*)d_ws + bsum_off);
        int* cnt     = (int*)((char*)d_ws + cnt_off);
        int* bucket  = (int*)((char*)d_ws + bucket_off);
        unsigned short* rank16 = (unsigned short*)((char*)d_ws + rank_off);

        zero_convert_kernel<<<2048, 256, 0, stream>>>(cnt, NPART * n, x, hhx, total4);
        hist_rank_part_kernel<<<histBlocks, 256, 0, stream>>>(dst, cnt, rank16, E, n);
        reduce_poff_kernel<<<nodeBlocks, 256, 0, stream>>>(cnt, deg, n);
        scanA_kernel<<<nb, 256, 0, stream>>>(deg, off, bsum, n);
        scanB_kernel<<<1, 256, 0, stream>>>(bsum, nb);
        scanC_kernel<<<nb, 256, 0, stream>>>(off, (int*)nullptr, bsum, n, E);
        addoff_kernel<<<nodeBlocks, 256, 0, stream>>>(cnt, off, n);
        fill_rank_part_kernel<<<fillBlocks, 256, 0, stream>>>(src, dst, rank16, cnt, bucket, E, n);

        // grid 2048 = 8 blocks/CU queued (cap 4 resident): HW rebalances tail
        fused_gin_h_kernel<<<2048, 512, 0, stream>>>(hhx, off, bucket, W0, eps0, hh1, n);
        fused_final_h_kernel<<<2048, 512, 0, stream>>>(hh1, off, bucket, W1, Wm, eps1, out, n);
    } else if (ws_size >= need_B) {
        float* h1    = (float*)((char*)d_ws + b_h1_off);
        int* off     = (int*)((char*)d_ws + b_off_off);
        int* deg     = (int*)((char*)d_ws + b_deg_off);
        int* cursor  = (int*)((char*)d_ws + b_cursor_off);
        int* bsum    = (int*)((char*)d_ws + b_bsum_off);
        int* bucket  = (int*)((char*)d_ws + b_bucket_off);

        zero_int_kernel<<<256, 256, 0, stream>>>(deg, n);
        hist_kernel<<<(E + 1023) / 1024, 256, 0, stream>>>(dst, deg, E);
        scanA_kernel<<<nb, 256, 0, stream>>>(deg, off, bsum, n);
        scanB_kernel<<<1, 256, 0, stream>>>(bsum, nb);
        scanC_kernel<<<nb, 256, 0, stream>>>(off, cursor, bsum, n, E);
        fill_kernel<<<(E + 255) / 256, 256, 0, stream>>>(src, dst, cursor, bucket, E);

        fused_gin_kernel<<<1024, 512, 0, stream>>>(x, off, bucket, W0, eps0, h1, n);
        fused_final_csr_kernel<<<768, 512, 0, stream>>>(h1, off, bucket, W1, Wm, eps1, out, n);
    } else {
        float* agg = (float*)d_ws;
        float* h1  = out;
        int scatterBlocks = (E + 3) / 4;

        init_scale_kernel<<<2048, 256, 0, stream>>>(x, eps0, agg, total4);
        scatter_kernel<<<scatterBlocks, 256, 0, stream>>>(x, src, dst, agg, E);
        gemm_relu_kernel<<<2048, 256, 0, stream>>>(agg, W0, h1, n);
        init_scale_kernel<<<2048, 256, 0, stream>>>(h1, eps1, agg, total4);
        scatter_kernel<<<scatterBlocks, 256, 0, stream>>>(h1, src, dst, agg, E);
        final_kernel<<<2048, 256, 0, stream>>>(agg, h1, W1, Wm, out, n);
    }
}